// Round 5
// baseline (32048.560 us; speedup 1.0000x reference)
//
#include <hip/hip_runtime.h>
#include <hip/hip_bf16.h>

// LSTM (B=64,T=512,I=512,H=1024,O=1), 2 layers + sigmoid head.
// R5: 64 WGs x 512 thr, 16 hidden units/WG (4 gate tiles of 16 rows).
//  - whh slice (64 rows x 1024) in LDS, XOR-swizzled (128KB, 1 WG/CU).
//  - 8 waves = 4 batch tiles x 2 tile-groups; per wave 2 output tiles,
//    64 MFMAs/step; h staged as two 16-u64 register chunks (fits <=128 VGPR
//    by design -- R3/R4 showed the allocator won't hold >~190 live).
//  - h exchanged via agent-scope RELAXED atomic u64 (L3-direct, no fences).
//  - Input GEMM for t+1 runs AFTER the arrive (off the critical path; R4 had
//    it before the arrive = on the path).
//  - Arrival: 8 groups x 8 WGs on separate lines; wave0 polls 8 counters,
//    releases siblings via LDS flag.

namespace {

constexpr int B_ = 64, T_ = 512, I_ = 512, H_ = 1024;
constexpr int NWG = 64, NTHR = 512;

typedef __attribute__((ext_vector_type(8))) short short8;
typedef __attribute__((ext_vector_type(4))) float f32x4;

#define MFMA16(a, b, c) __builtin_amdgcn_mfma_f32_16x16x32_bf16((a), (b), (c), 0, 0, 0)

__device__ __forceinline__ float sigm(float x)  { return 1.f / (1.f + __expf(-x)); }
__device__ __forceinline__ float tanhx(float x) { return 2.f / (1.f + __expf(-2.f * x)) - 1.f; }

__device__ __forceinline__ unsigned f2bf(float f) {
  unsigned u = __float_as_uint(f);
  unsigned rnd = 0x7FFFu + ((u >> 16) & 1u);
  return (u + rnd) >> 16;   // low 16 bits valid
}
__device__ __forceinline__ float bf2f(unsigned short s) {
  return __uint_as_float(((unsigned)s) << 16);
}

__device__ __forceinline__ short8 pack2(unsigned long long a, unsigned long long b) {
  union { unsigned long long q[2]; short8 v; } u;
  u.q[0] = a; u.q[1] = b;
  return u.v;
}

__global__ void cvt_bf16_k(const float* __restrict__ src, unsigned short* __restrict__ dst, int n4) {
  int i = blockIdx.x * 256 + threadIdx.x;
  if (i >= n4) return;
  float4 v = reinterpret_cast<const float4*>(src)[i];
  ushort4 o;
  o.x = (unsigned short)f2bf(v.x); o.y = (unsigned short)f2bf(v.y);
  o.z = (unsigned short)f2bf(v.z); o.w = (unsigned short)f2bf(v.w);
  reinterpret_cast<ushort4*>(dst)[i] = o;
}

__global__ void zero_init_k(unsigned short* __restrict__ h1, unsigned short* __restrict__ h2,
                            unsigned* __restrict__ bar) {
  int i = blockIdx.x * 256 + threadIdx.x;
  if (i < B_ * H_) h1[i] = 0;           // h1 slab 0 (t=-1 state)
  if (i < 2 * B_ * H_) h2[i] = 0;       // h2 ping-pong slabs
  if (i < 1024) bar[i] = 0;             // both layers' barrier counters
}

// bars per layer: group g (8 groups of 8 WGs) counter at bars[g*32]
// (separate 128B lines). Monotonic: after all arrivals of iteration t, each
// counter == 8*(t+1). wait(t): all >= 8*t.
// hout: [slabs][B][H] bf16; read slab t&wr_mask, write slab (t+1)&wr_mask.
template<int K_IN>
__global__ __launch_bounds__(NTHR, 2) void lstm_layer(
    const unsigned short* __restrict__ in, size_t in_stride_t, size_t in_stride_b,
    const unsigned short* __restrict__ w_in,   // [4H][K_IN] bf16
    const unsigned short* __restrict__ w_hh,   // [4H][H] bf16
    const float* __restrict__ b_ih, const float* __restrict__ b_hh,
    unsigned short* __restrict__ hout, int wr_mask,
    unsigned* __restrict__ bars)
{
  constexpr int KT_IN = K_IN / 32;   // 16 (L0) or 32 (L1)

  __shared__ unsigned short s_whh[64 * H_];   // 128 KB
  __shared__ int rel_flag;

  const int tid  = threadIdx.x;
  const int wg   = blockIdx.x;      // 0..63
  const int wave = tid >> 6;        // 0..7
  const int lane = tid & 63;
  const int bt   = wave & 3;        // batch tile
  const int rtg  = wave >> 2;       // tile-group 0..1 (gate tiles {0,1} / {2,3})
  const int j0   = wg * 16;         // first hidden unit owned by this WG
  const int n    = lane & 15;
  const int k0   = (lane >> 4) * 8;
  const int swz_n = (n & 7) << 3;
  const int arow = bt * 16 + n;     // batch row (A fragment)

  if (tid == 0) rel_flag = 0;

  // ---- stage whh slice (64 rows x H) into LDS, XOR swizzle ----
  // slice row r: tile gt=r>>4, nr=r&15 -> gate=nr>>2, unit=gt*4+(nr&3)
  for (int c = tid; c < 64 * (H_ / 8); c += NTHR) {
    int r  = c >> 7;              // H_/8 = 128 chunks per row
    int kc = (c & 127) * 8;
    int grow = ((r & 15) >> 2) * H_ + j0 + (r >> 4) * 4 + (r & 3);
    *reinterpret_cast<short8*>(&s_whh[r * H_ + (kc ^ ((r & 7) << 3))]) =
        *reinterpret_cast<const short8*>(&w_hh[(size_t)grow * H_ + kc]);
  }

  const int gt0 = rtg * 2, gt1 = rtg * 2 + 1;
  const int grow0 = (n >> 2) * H_ + j0 + gt0 * 4 + (n & 3);
  const int grow1 = (n >> 2) * H_ + j0 + gt1 * 4 + (n & 3);
  const float bias0 = b_ih[grow0] + b_hh[grow0];
  const float bias1 = b_ih[grow1] + b_hh[grow1];
  const int r0off = (gt0 * 16 + n) * H_;
  const int r1off = (gt1 * 16 + n) * H_;

  const unsigned short* a_in_base = in + (size_t)arow * in_stride_b + k0;
  const unsigned short* w0p = w_in + (size_t)grow0 * K_IN + k0;
  const unsigned short* w1p = w_in + (size_t)grow1 * K_IN + k0;

  const int eb = bt * 16 + (lane >> 2);   // batch for elementwise
  const int eu = lane & 3;
  float cst0 = 0.f, cst1 = 0.f;

  unsigned* grp = bars + (wg >> 3) * 32;

  __syncthreads();   // whh staged, rel_flag visible

  // ---- chunked hh helpers (static indexing only) ----
  const size_t lane_qoff = (size_t)arow * (H_ / 4) + (size_t)(k0 >> 2);

  f32x4 acc0 = {0.f, 0.f, 0.f, 0.f}, acc1 = {0.f, 0.f, 0.f, 0.f};

  // prologue: input-GEMM partial for t=0
  {
    const unsigned short* a_in = a_in_base;
    #pragma unroll 8
    for (int kk = 0; kk < KT_IN; ++kk) {
      short8 av = *reinterpret_cast<const short8*>(a_in + kk * 32);
      acc0 = MFMA16(av, *reinterpret_cast<const short8*>(w0p + kk * 32), acc0);
      acc1 = MFMA16(av, *reinterpret_cast<const short8*>(w1p + kk * 32), acc1);
    }
  }

  for (int t = 0; t < T_; ++t) {
    // ---- wait for h[t] ----
    if (t > 0) {
      if (wave == 0) {
        const unsigned tgt = (unsigned)t * 8u;
        for (;;) {
          unsigned v = 0xFFFFFFFFu;
          if (lane < 8)
            v = __hip_atomic_load(bars + lane * 32, __ATOMIC_RELAXED, __HIP_MEMORY_SCOPE_AGENT);
          if (__all((int)(lane >= 8 || v >= tgt))) break;
          __builtin_amdgcn_s_sleep(1);
        }
        if (lane == 0)
          __hip_atomic_store(&rel_flag, t, __ATOMIC_RELEASE, __HIP_MEMORY_SCOPE_WORKGROUP);
      } else {
        while (__hip_atomic_load(&rel_flag, __ATOMIC_ACQUIRE, __HIP_MEMORY_SCOPE_WORKGROUP) < t)
          __builtin_amdgcn_s_sleep(1);
      }
    }

    // ---- recurrent GEMM: 4 chunks of 8 k-tiles, double-buffered q0/q1 ----
    const unsigned long long* hq = reinterpret_cast<const unsigned long long*>(hout)
        + (size_t)(t & wr_mask) * (B_ * H_ / 4) + lane_qoff;

    unsigned long long q0[16], q1[16];
    auto loadc = [&](unsigned long long (&Q)[16], int c) {
      #pragma unroll
      for (int j = 0; j < 8; ++j) {
        Q[2 * j]     = __hip_atomic_load(hq + c * 64 + j * 8,     __ATOMIC_RELAXED, __HIP_MEMORY_SCOPE_AGENT);
        Q[2 * j + 1] = __hip_atomic_load(hq + c * 64 + j * 8 + 1, __ATOMIC_RELAXED, __HIP_MEMORY_SCOPE_AGENT);
      }
    };
    auto mfmac = [&](unsigned long long (&Q)[16], int c) {
      #pragma unroll
      for (int j = 0; j < 8; ++j) {
        const int kk = c * 8 + j;
        short8 av = pack2(Q[2 * j], Q[2 * j + 1]);
        const int col = (k0 + kk * 32) ^ swz_n;
        acc0 = MFMA16(av, *reinterpret_cast<const short8*>(&s_whh[r0off + col]), acc0);
        acc1 = MFMA16(av, *reinterpret_cast<const short8*>(&s_whh[r1off + col]), acc1);
      }
    };
    loadc(q0, 0);
    loadc(q1, 1);
    mfmac(q0, 0);
    loadc(q0, 2);
    mfmac(q1, 1);
    loadc(q1, 3);
    mfmac(q0, 2);
    mfmac(q1, 3);

    // ---- elementwise per tile (wave-local shfl redistribution) ----
    const size_t slab = (size_t)((t + 1) & wr_mask) * (B_ * H_);
    auto ewtile = [&](f32x4 acc, float bias, float& cst, int gt) {
      float pg[4];
      const int rsel  = (lane >> 2) & 3;
      const int sbase = (lane & 48) | (lane & 3);
      #pragma unroll
      for (int g = 0; g < 4; ++g) {
        int src = sbase | (g << 2);
        float t0 = __shfl(acc[0] + bias, src, 64);
        float t1 = __shfl(acc[1] + bias, src, 64);
        float t2 = __shfl(acc[2] + bias, src, 64);
        float t3 = __shfl(acc[3] + bias, src, 64);
        pg[g] = (rsel == 0) ? t0 : (rsel == 1) ? t1 : (rsel == 2) ? t2 : t3;
      }
      float gi = sigm(pg[0]);
      float gf = sigm(pg[1]);
      float gg = tanhx(pg[2]);
      float go = sigm(pg[3]);
      cst = gf * cst + gi * gg;
      float hv = go * tanhx(cst);

      unsigned hv16 = f2bf(hv) & 0xFFFFu;
      const int lb = lane & ~3;
      unsigned v1 = __shfl(hv16, lb | 1, 64);
      unsigned v2 = __shfl(hv16, lb | 2, 64);
      unsigned v3 = __shfl(hv16, lb | 3, 64);
      if (eu == 0) {
        unsigned long long qv = (unsigned long long)(hv16 | (v1 << 16)) |
                                ((unsigned long long)(v2 | (v3 << 16)) << 32);
        unsigned long long* dst = (unsigned long long*)
            (hout + slab + (size_t)eb * H_ + j0 + gt * 4);
        __hip_atomic_store(dst, qv, __ATOMIC_RELAXED, __HIP_MEMORY_SCOPE_AGENT);
      }
    };
    ewtile(acc0, bias0, cst0, gt0);
    ewtile(acc1, bias1, cst1, gt1);

    // ---- arrive (barrier drains all waves' bypass stores first) ----
    __syncthreads();
    if (tid == 0)
      __hip_atomic_fetch_add(grp, 1u, __ATOMIC_RELAXED, __HIP_MEMORY_SCOPE_AGENT);

    // ---- input GEMM for t+1 (OFF the critical path: overlaps other WGs'
    //      arrivals and the release round trip) ----
    const int tn = (t + 1 < T_) ? t + 1 : t;
    f32x4 na0 = {0.f, 0.f, 0.f, 0.f}, na1 = {0.f, 0.f, 0.f, 0.f};
    const unsigned short* a_in = a_in_base + (size_t)tn * in_stride_t;
    #pragma unroll 8
    for (int kk = 0; kk < KT_IN; ++kk) {
      short8 av = *reinterpret_cast<const short8*>(a_in + kk * 32);
      na0 = MFMA16(av, *reinterpret_cast<const short8*>(w0p + kk * 32), na0);
      na1 = MFMA16(av, *reinterpret_cast<const short8*>(w1p + kk * 32), na1);
    }
    acc0 = na0;
    acc1 = na1;
  }
}

__global__ void out_head(const unsigned short* __restrict__ h2,
                         const float* __restrict__ W_out,
                         const float* __restrict__ b_out,
                         float* __restrict__ out) {
  int b = blockIdx.x;      // 64
  int lane = threadIdx.x;  // 64 (one wave)
  float s = 0.f;
  for (int k = lane; k < H_; k += 64)
    s += bf2f(h2[(size_t)b * H_ + k]) * W_out[k];
  #pragma unroll
  for (int off = 32; off; off >>= 1) s += __shfl_down(s, off, 64);
  if (lane == 0) out[b] = sigm(s + b_out[0]);
}

} // namespace

extern "C" void kernel_launch(void* const* d_in, const int* in_sizes, int n_in,
                              void* d_out, int out_size, void* d_ws, size_t ws_size,
                              hipStream_t stream) {
  const float* x    = (const float*)d_in[0];
  const float* Wih0 = (const float*)d_in[1];
  const float* Whh0 = (const float*)d_in[2];
  const float* bih0 = (const float*)d_in[3];
  const float* bhh0 = (const float*)d_in[4];
  const float* Wih1 = (const float*)d_in[5];
  const float* Whh1 = (const float*)d_in[6];
  const float* bih1 = (const float*)d_in[7];
  const float* bhh1 = (const float*)d_in[8];
  const float* Wout = (const float*)d_in[9];
  const float* bout = (const float*)d_in[10];
  float* out = (float*)d_out;

  char* ws = (char*)d_ws;
  size_t off = 0;
  auto alloc = [&](size_t bytes) -> char* {
    char* p = ws + off;
    off += (bytes + 255) & ~(size_t)255;
    return p;
  };
  unsigned* bar        = (unsigned*)alloc(4096);  // 2 layers x 512 u32
  unsigned short* xb   = (unsigned short*)alloc((size_t)B_ * T_ * I_ * 2);
  unsigned short* wih0 = (unsigned short*)alloc((size_t)4 * H_ * I_ * 2);
  unsigned short* whh0 = (unsigned short*)alloc((size_t)4 * H_ * H_ * 2);
  unsigned short* wih1 = (unsigned short*)alloc((size_t)4 * H_ * H_ * 2);
  unsigned short* whh1 = (unsigned short*)alloc((size_t)4 * H_ * H_ * 2);
  unsigned short* h1   = (unsigned short*)alloc((size_t)(T_ + 1) * B_ * H_ * 2);
  unsigned short* h2   = (unsigned short*)alloc((size_t)2 * B_ * H_ * 2);

  auto cvt = [&](const float* s, unsigned short* d, int nelem) {
    int n4 = nelem / 4;
    cvt_bf16_k<<<(n4 + 255) / 256, 256, 0, stream>>>(s, d, n4);
  };
  cvt(x,    xb,   B_ * T_ * I_);
  cvt(Wih0, wih0, 4 * H_ * I_);
  cvt(Whh0, whh0, 4 * H_ * H_);
  cvt(Wih1, wih1, 4 * H_ * H_);
  cvt(Whh1, whh1, 4 * H_ * H_);
  zero_init_k<<<(2 * B_ * H_ + 255) / 256, 256, 0, stream>>>(h1, h2, bar);

  // layer 0: input x [B][T][I] (stride_t = I, stride_b = T*I), full h1 record
  lstm_layer<I_><<<NWG, NTHR, 0, stream>>>(
      xb, (size_t)I_, (size_t)T_ * I_,
      wih0, whh0, bih0, bhh0, h1, 1023, bar);

  // layer 1: input h1 slabs 1..512 ([t][b][k]: stride_t = B*H, stride_b = H),
  // h2 ping-pong (final h at slab 0 since T even)
  lstm_layer<H_><<<NWG, NTHR, 0, stream>>>(
      h1 + B_ * H_, (size_t)B_ * H_, (size_t)H_,
      wih1, whh1, bih1, bhh1, h2, 1, bar + 512);

  out_head<<<B_, 64, 0, stream>>>(h2, Wout, bout, out);
}

// Round 7
// 10907.587 us; speedup vs baseline: 2.9382x; 2.9382x over previous
//
#include <hip/hip_runtime.h>
#include <hip/hip_bf16.h>

// LSTM (B=64,T=512,I=512,H=1024,O=1), 2 layers + sigmoid head.
// R7 = R6 with the layer-1 barrier-aliasing bug fixed (+ reverse slab order).
//  - h written via agent-scope RELAXED atomic u64 (write-through to MALL);
//    h READ via PLAIN CACHED loads from a per-step FRESH slab. Write-once
//    addresses => no fences. Slabs in REVERSE address order so L2
//    prefetch-ahead never lands in a yet-unwritten slab.
//  - 256 WGs x 256 thr (4 waves), 4 units/WG, W_in/W_hh slices in LDS
//    (XOR-swizzled), 2 WGs/CU.
//  - Arrive: 32 groups x 8 WGs (separate 128B lines), RELEASE fetch_add;
//    wave0 polls all 32 lines (lane<32 + __all), LDS flag for siblings.
//    Input GEMM for t+1 runs after arrive (in the release shadow).
//  - Barrier region: 16KB, layer0 at bar[0], layer1 at bar[2048] -- both
//    inside the allocation and zeroed (R6 pointed layer1 into wih0!).

namespace {

constexpr int B_ = 64, T_ = 512, I_ = 512, H_ = 1024;
constexpr int NWG = 256, NTHR = 256;
constexpr int BH = B_ * H_;

typedef __attribute__((ext_vector_type(8))) short short8;
typedef __attribute__((ext_vector_type(4))) float f32x4;

#define MFMA16(a, b, c) __builtin_amdgcn_mfma_f32_16x16x32_bf16((a), (b), (c), 0, 0, 0)

__device__ __forceinline__ float sigm(float x)  { return 1.f / (1.f + __expf(-x)); }
__device__ __forceinline__ float tanhx(float x) { return 2.f / (1.f + __expf(-2.f * x)) - 1.f; }

__device__ __forceinline__ unsigned f2bf(float f) {
  unsigned u = __float_as_uint(f);
  unsigned rnd = 0x7FFFu + ((u >> 16) & 1u);
  return (u + rnd) >> 16;   // low 16 bits valid
}
__device__ __forceinline__ float bf2f(unsigned short s) {
  return __uint_as_float(((unsigned)s) << 16);
}

__device__ __forceinline__ short8 pack2(unsigned long long a, unsigned long long b) {
  union { unsigned long long q[2]; short8 v; } u;
  u.q[0] = a; u.q[1] = b;
  return u.v;
}

__global__ void cvt_bf16_k(const float* __restrict__ src, unsigned short* __restrict__ dst, int n4) {
  int i = blockIdx.x * 256 + threadIdx.x;
  if (i >= n4) return;
  float4 v = reinterpret_cast<const float4*>(src)[i];
  ushort4 o;
  o.x = (unsigned short)f2bf(v.x); o.y = (unsigned short)f2bf(v.y);
  o.z = (unsigned short)f2bf(v.z); o.w = (unsigned short)f2bf(v.w);
  reinterpret_cast<ushort4*>(dst)[i] = o;
}

// zero slab-0 of both records (at REVERSED position T_) and all barrier lines
__global__ void zero_init_k(unsigned short* __restrict__ h1, unsigned short* __restrict__ h2,
                            unsigned* __restrict__ bar) {
  int i = blockIdx.x * 256 + threadIdx.x;
  if (i < BH) h1[(size_t)T_ * BH + i] = 0;
  if (i < BH) h2[(size_t)T_ * BH + i] = 0;
  if (i < 4096) bar[i] = 0;             // 16KB barrier region (both layers)
}

// bars per layer: 32 group lines (8 WGs each), counter g at bars[g*32].
// Monotonic: after all arrivals of step t each counter == 8*(t+1).
// h record (FRESH): slab s at hrec + (T_-s)*BH (reverse order).
//   read slab t  -> hrec + (T_-t)*BH ; write slab t+1 -> hrec + (T_-t-1)*BH
template<int K_IN>
__global__ __launch_bounds__(NTHR, 2) void lstm_layer(
    const unsigned short* __restrict__ in, long long in_stride_t, long long in_stride_b,
    const unsigned short* __restrict__ w_in,   // [4H][K_IN] bf16
    const unsigned short* __restrict__ w_hh,   // [4H][H] bf16
    const float* __restrict__ b_ih, const float* __restrict__ b_hh,
    unsigned short* __restrict__ hrec,
    unsigned* __restrict__ bars)
{
  __shared__ unsigned short s_win[16 * K_IN];
  __shared__ unsigned short s_whh[16 * H_];
  __shared__ int rel_flag;

  const int tid  = threadIdx.x;
  const int wg   = blockIdx.x;      // 0..255
  const int wave = tid >> 6;        // 0..3 -> batch tile
  const int lane = tid & 63;
  const int j0   = wg * 4;          // first hidden unit owned by this WG
  const int n    = lane & 15;       // gate-row (D column) this lane covers

  unsigned* grp = bars + (wg >> 3) * 32;   // 32 groups of 8 WGs

  if (tid == 0) rel_flag = 0;

  // ---- stage W slices into LDS with XOR swizzle (shorts: k ^= (r&7)<<3) ----
  constexpr int CH_IN = K_IN / 8;
  for (int c = tid; c < 16 * CH_IN; c += NTHR) {
    int r = c / CH_IN;
    int kc = (c % CH_IN) * 8;
    int grow = (r >> 2) * H_ + j0 + (r & 3);
    *reinterpret_cast<short8*>(&s_win[r * K_IN + (kc ^ ((r & 7) << 3))]) =
        *reinterpret_cast<const short8*>(&w_in[(size_t)grow * K_IN + kc]);
  }
  constexpr int CH_HH = H_ / 8;
  for (int c = tid; c < 16 * CH_HH; c += NTHR) {
    int r = c / CH_HH;
    int kc = (c % CH_HH) * 8;
    int grow = (r >> 2) * H_ + j0 + (r & 3);
    *reinterpret_cast<short8*>(&s_whh[r * H_ + (kc ^ ((r & 7) << 3))]) =
        *reinterpret_cast<const short8*>(&w_hh[(size_t)grow * H_ + kc]);
  }
  const int grow_n = (n >> 2) * H_ + j0 + (n & 3);
  const float bias_n = b_ih[grow_n] + b_hh[grow_n];
  __syncthreads();

  // ---- per-lane MFMA addressing ----
  const int k0    = (lane >> 4) * 8;      // k offset within 32-wide K tile
  const int arow  = wave * 16 + n;        // batch row (A fragment)
  const int swz_n = (n & 7) << 3;
  // ---- elementwise identity: thread -> (batch, unit) ----
  const int eb = wave * 16 + (lane >> 2); // batch 0..63
  const int eu = lane & 3;                // unit 0..3
  float cst = 0.f;

  const unsigned short* a_in_base = in + (long long)arow * in_stride_b + k0;

  f32x4 acc = {0.f, 0.f, 0.f, 0.f};
  // prologue: input GEMM partial for t=0
  #pragma unroll 8
  for (int kk = 0; kk < K_IN / 32; ++kk)
    acc = MFMA16(*reinterpret_cast<const short8*>(a_in_base + kk * 32),
                 *reinterpret_cast<const short8*>(&s_win[n * K_IN + ((k0 + kk * 32) ^ swz_n)]),
                 acc);

  for (int t = 0; t < T_; ++t) {
    // ---- wait for h[t] (all WGs' step t-1 stores at coherence point) ----
    if (t > 0) {
      if (wave == 0) {
        const unsigned tgt = (unsigned)t * 8u;
        for (;;) {
          unsigned v = 0xFFFFFFFFu;
          if (lane < 32)
            v = __hip_atomic_load(bars + lane * 32, __ATOMIC_RELAXED, __HIP_MEMORY_SCOPE_AGENT);
          if (__all((int)(lane >= 32 || v >= tgt))) break;
          __builtin_amdgcn_s_sleep(2);
        }
        if (lane == 0)
          __hip_atomic_store(&rel_flag, t, __ATOMIC_RELEASE, __HIP_MEMORY_SCOPE_WORKGROUP);
      } else {
        while (__hip_atomic_load(&rel_flag, __ATOMIC_ACQUIRE, __HIP_MEMORY_SCOPE_WORKGROUP) < t)
          __builtin_amdgcn_s_sleep(1);
      }
    }

    // ---- recurrent GEMM: h[slab t] @ W_hh^T (plain cached loads) ----
    const unsigned short* a_h = hrec + (size_t)(T_ - t) * BH + (size_t)arow * H_ + k0;
    #pragma unroll 8
    for (int kk = 0; kk < H_ / 32; ++kk) {
      short8 av = *reinterpret_cast<const short8*>(a_h + kk * 32);
      short8 bv = *reinterpret_cast<const short8*>(&s_whh[n * H_ + ((k0 + kk * 32) ^ swz_n)]);
      acc = MFMA16(av, bv, acc);
    }
    acc[0] += bias_n; acc[1] += bias_n; acc[2] += bias_n; acc[3] += bias_n;

    // ---- redistribute gates within the wave, elementwise ----
    const int rsel  = (lane >> 2) & 3;
    const int sbase = (lane & 48) | (lane & 3);
    float pg[4];
    #pragma unroll
    for (int g = 0; g < 4; ++g) {
      int src = sbase | (g << 2);
      float t0 = __shfl(acc[0], src, 64);
      float t1 = __shfl(acc[1], src, 64);
      float t2 = __shfl(acc[2], src, 64);
      float t3 = __shfl(acc[3], src, 64);
      pg[g] = (rsel == 0) ? t0 : (rsel == 1) ? t1 : (rsel == 2) ? t2 : t3;
    }
    float gi = sigm(pg[0]);
    float gf = sigm(pg[1]);
    float gg = tanhx(pg[2]);
    float go = sigm(pg[3]);
    cst = gf * cst + gi * gg;
    float hv = go * tanhx(cst);

    // pack 4 units for batch eb into one u64, write-through store to slab t+1
    unsigned hv16 = f2bf(hv) & 0xFFFFu;
    const int lb = lane & ~3;
    unsigned v1 = __shfl(hv16, lb | 1, 64);
    unsigned v2 = __shfl(hv16, lb | 2, 64);
    unsigned v3 = __shfl(hv16, lb | 3, 64);
    if (eu == 0) {
      unsigned long long qv = (unsigned long long)(hv16 | (v1 << 16)) |
                              ((unsigned long long)(v2 | (v3 << 16)) << 32);
      unsigned long long* dst = (unsigned long long*)
          (hrec + (size_t)(T_ - t - 1) * BH + (size_t)eb * H_ + j0);
      __hip_atomic_store(dst, qv, __ATOMIC_RELAXED, __HIP_MEMORY_SCOPE_AGENT);
    }

    // ---- arrive: barrier drains all waves' stores; RELEASE orders at MALL ----
    __syncthreads();
    if (tid == 0)
      __hip_atomic_fetch_add(grp, 1u, __ATOMIC_RELEASE, __HIP_MEMORY_SCOPE_AGENT);

    // ---- input GEMM for t+1 (in the arrive->release shadow) ----
    const int tn = (t + 1 < T_) ? t + 1 : t;
    f32x4 na = {0.f, 0.f, 0.f, 0.f};
    const unsigned short* a_in = a_in_base + (long long)tn * in_stride_t;
    #pragma unroll 8
    for (int kk = 0; kk < K_IN / 32; ++kk)
      na = MFMA16(*reinterpret_cast<const short8*>(a_in + kk * 32),
                  *reinterpret_cast<const short8*>(&s_win[n * K_IN + ((k0 + kk * 32) ^ swz_n)]),
                  na);
    acc = na;
  }
}

__global__ void out_head(const unsigned short* __restrict__ h2,
                         const float* __restrict__ W_out,
                         const float* __restrict__ b_out,
                         float* __restrict__ out) {
  int b = blockIdx.x;      // 64
  int lane = threadIdx.x;  // 64 (one wave)
  float s = 0.f;
  for (int k = lane; k < H_; k += 64)
    s += bf2f(h2[(size_t)b * H_ + k]) * W_out[k];
  #pragma unroll
  for (int off = 32; off; off >>= 1) s += __shfl_down(s, off, 64);
  if (lane == 0) out[b] = sigm(s + b_out[0]);
}

} // namespace

extern "C" void kernel_launch(void* const* d_in, const int* in_sizes, int n_in,
                              void* d_out, int out_size, void* d_ws, size_t ws_size,
                              hipStream_t stream) {
  const float* x    = (const float*)d_in[0];
  const float* Wih0 = (const float*)d_in[1];
  const float* Whh0 = (const float*)d_in[2];
  const float* bih0 = (const float*)d_in[3];
  const float* bhh0 = (const float*)d_in[4];
  const float* Wih1 = (const float*)d_in[5];
  const float* Whh1 = (const float*)d_in[6];
  const float* bih1 = (const float*)d_in[7];
  const float* bhh1 = (const float*)d_in[8];
  const float* Wout = (const float*)d_in[9];
  const float* bout = (const float*)d_in[10];
  float* out = (float*)d_out;

  char* ws = (char*)d_ws;
  size_t off = 0;
  auto alloc = [&](size_t bytes) -> char* {
    char* p = ws + off;
    off += (bytes + 4095) & ~(size_t)4095;   // 4KB-align every region
    return p;
  };
  const size_t REC = (size_t)(T_ + 1) * BH * 2;       // 67.2 MB (513 slabs)

  unsigned* bar        = (unsigned*)alloc(16384);     // 4096 u32: L0 at 0, L1 at 2048
  unsigned short* xb   = (unsigned short*)alloc((size_t)B_ * T_ * I_ * 2);
  unsigned short* wih0 = (unsigned short*)alloc((size_t)4 * H_ * I_ * 2);
  unsigned short* whh0 = (unsigned short*)alloc((size_t)4 * H_ * H_ * 2);
  unsigned short* wih1 = (unsigned short*)alloc((size_t)4 * H_ * H_ * 2);
  unsigned short* whh1 = (unsigned short*)alloc((size_t)4 * H_ * H_ * 2);
  unsigned short* h1   = (unsigned short*)alloc(REC);
  unsigned short* h2   = (unsigned short*)alloc(REC);

  auto cvt = [&](const float* s, unsigned short* d, int nelem) {
    int n4 = nelem / 4;
    cvt_bf16_k<<<(n4 + 255) / 256, 256, 0, stream>>>(s, d, n4);
  };
  cvt(x,    xb,   B_ * T_ * I_);
  cvt(Wih0, wih0, 4 * H_ * I_);
  cvt(Whh0, whh0, 4 * H_ * H_);
  cvt(Wih1, wih1, 4 * H_ * H_);
  cvt(Whh1, whh1, 4 * H_ * H_);
  zero_init_k<<<(BH + 255) / 256, 256, 0, stream>>>(h1, h2, bar);

  // layer 0: xb [B][T][I] bf16 (stride_t=I, stride_b=T*I), fresh reversed record
  lstm_layer<I_><<<NWG, NTHR, 0, stream>>>(
      xb, (long long)I_, (long long)T_ * I_,
      wih0, whh0, bih0, bhh0, h1, bar);

  // layer 1: input h1 slabs s=1..512 at h1+(T_-s)*BH -> base h1+(T_-1)*BH,
  // stride_t = -BH; within-slab [b][k]: stride_b = H
  lstm_layer<H_><<<NWG, NTHR, 0, stream>>>(
      h1 + (size_t)(T_ - 1) * BH, -(long long)BH, (long long)H_,
      wih1, whh1, bih1, bhh1, h2, bar + 2048);

  // final h2 = slab T at reversed offset 0
  out_head<<<B_, 64, 0, stream>>>(h2, Wout, bout, out);
}

// Round 8
// 7840.827 us; speedup vs baseline: 4.0874x; 1.3911x over previous
//
#include <hip/hip_runtime.h>
#include <hip/hip_bf16.h>

// LSTM (B=64,T=512,I=512,H=1024,O=1), 2 layers + sigmoid head.
// R8 = R7 with the arrive atomic downgraded RELEASE -> RELAXED.
//   Rationale: agent-scope release RMW lowers to buffer_wbl2 (+wait) on
//   multi-XCD gfx9xx -- a per-WG per-step L2 writeback, the same class of
//   cache-maintenance tax that made R2 slow (its acquire fence = buffer_inv).
//   The release is redundant: __syncthreads before the arrive drains
//   vmcnt(0), and the h stores are sc0sc1 write-through, so their acks mean
//   "data at MALL" before the RMW issues. Consumers that see the counter see h.
//   wave0's own post-poll loads are ordered by a WORKGROUP acquire fence
//   (s_waitcnt only, no cache ops).
// Everything else identical to R7:
//  - h written via agent-scope RELAXED atomic u64 (write-through to MALL);
//    h read via plain cached loads from per-step FRESH slabs in REVERSE
//    address order (write-once lines; prefetch-ahead lands on consumed slabs).
//  - 256 WGs x 256 thr (4 waves), 4 units/WG, W_in/W_hh slices in LDS
//    (XOR-swizzled).
//  - Arrive: 32 group lines x 8 WGs; wave0 polls all 32 lines (lane<32 +
//    __all), LDS flag for siblings. Input GEMM for t+1 after the arrive.

namespace {

constexpr int B_ = 64, T_ = 512, I_ = 512, H_ = 1024;
constexpr int NWG = 256, NTHR = 256;
constexpr int BH = B_ * H_;

typedef __attribute__((ext_vector_type(8))) short short8;
typedef __attribute__((ext_vector_type(4))) float f32x4;

#define MFMA16(a, b, c) __builtin_amdgcn_mfma_f32_16x16x32_bf16((a), (b), (c), 0, 0, 0)

__device__ __forceinline__ float sigm(float x)  { return 1.f / (1.f + __expf(-x)); }
__device__ __forceinline__ float tanhx(float x) { return 2.f / (1.f + __expf(-2.f * x)) - 1.f; }

__device__ __forceinline__ unsigned f2bf(float f) {
  unsigned u = __float_as_uint(f);
  unsigned rnd = 0x7FFFu + ((u >> 16) & 1u);
  return (u + rnd) >> 16;   // low 16 bits valid
}
__device__ __forceinline__ float bf2f(unsigned short s) {
  return __uint_as_float(((unsigned)s) << 16);
}

__global__ void cvt_bf16_k(const float* __restrict__ src, unsigned short* __restrict__ dst, int n4) {
  int i = blockIdx.x * 256 + threadIdx.x;
  if (i >= n4) return;
  float4 v = reinterpret_cast<const float4*>(src)[i];
  ushort4 o;
  o.x = (unsigned short)f2bf(v.x); o.y = (unsigned short)f2bf(v.y);
  o.z = (unsigned short)f2bf(v.z); o.w = (unsigned short)f2bf(v.w);
  reinterpret_cast<ushort4*>(dst)[i] = o;
}

// zero slab-0 of both records (at REVERSED position T_) and all barrier lines
__global__ void zero_init_k(unsigned short* __restrict__ h1, unsigned short* __restrict__ h2,
                            unsigned* __restrict__ bar) {
  int i = blockIdx.x * 256 + threadIdx.x;
  if (i < BH) h1[(size_t)T_ * BH + i] = 0;
  if (i < BH) h2[(size_t)T_ * BH + i] = 0;
  if (i < 4096) bar[i] = 0;             // 16KB barrier region (both layers)
}

// bars per layer: 32 group lines (8 WGs each), counter g at bars[g*32].
// Monotonic: after all arrivals of step t each counter == 8*(t+1).
// h record (FRESH): slab s at hrec + (T_-s)*BH (reverse order).
//   read slab t  -> hrec + (T_-t)*BH ; write slab t+1 -> hrec + (T_-t-1)*BH
template<int K_IN>
__global__ __launch_bounds__(NTHR, 2) void lstm_layer(
    const unsigned short* __restrict__ in, long long in_stride_t, long long in_stride_b,
    const unsigned short* __restrict__ w_in,   // [4H][K_IN] bf16
    const unsigned short* __restrict__ w_hh,   // [4H][H] bf16
    const float* __restrict__ b_ih, const float* __restrict__ b_hh,
    unsigned short* __restrict__ hrec,
    unsigned* __restrict__ bars)
{
  __shared__ unsigned short s_win[16 * K_IN];
  __shared__ unsigned short s_whh[16 * H_];
  __shared__ int rel_flag;

  const int tid  = threadIdx.x;
  const int wg   = blockIdx.x;      // 0..255
  const int wave = tid >> 6;        // 0..3 -> batch tile
  const int lane = tid & 63;
  const int j0   = wg * 4;          // first hidden unit owned by this WG
  const int n    = lane & 15;       // gate-row (D column) this lane covers

  unsigned* grp = bars + (wg >> 3) * 32;   // 32 groups of 8 WGs

  if (tid == 0) rel_flag = 0;

  // ---- stage W slices into LDS with XOR swizzle (shorts: k ^= (r&7)<<3) ----
  constexpr int CH_IN = K_IN / 8;
  for (int c = tid; c < 16 * CH_IN; c += NTHR) {
    int r = c / CH_IN;
    int kc = (c % CH_IN) * 8;
    int grow = (r >> 2) * H_ + j0 + (r & 3);
    *reinterpret_cast<short8*>(&s_win[r * K_IN + (kc ^ ((r & 7) << 3))]) =
        *reinterpret_cast<const short8*>(&w_in[(size_t)grow * K_IN + kc]);
  }
  constexpr int CH_HH = H_ / 8;
  for (int c = tid; c < 16 * CH_HH; c += NTHR) {
    int r = c / CH_HH;
    int kc = (c % CH_HH) * 8;
    int grow = (r >> 2) * H_ + j0 + (r & 3);
    *reinterpret_cast<short8*>(&s_whh[r * H_ + (kc ^ ((r & 7) << 3))]) =
        *reinterpret_cast<const short8*>(&w_hh[(size_t)grow * H_ + kc]);
  }
  const int grow_n = (n >> 2) * H_ + j0 + (n & 3);
  const float bias_n = b_ih[grow_n] + b_hh[grow_n];
  __syncthreads();

  // ---- per-lane MFMA addressing ----
  const int k0    = (lane >> 4) * 8;      // k offset within 32-wide K tile
  const int arow  = wave * 16 + n;        // batch row (A fragment)
  const int swz_n = (n & 7) << 3;
  // ---- elementwise identity: thread -> (batch, unit) ----
  const int eb = wave * 16 + (lane >> 2); // batch 0..63
  const int eu = lane & 3;                // unit 0..3
  float cst = 0.f;

  const unsigned short* a_in_base = in + (long long)arow * in_stride_b + k0;

  f32x4 acc = {0.f, 0.f, 0.f, 0.f};
  // prologue: input GEMM partial for t=0
  #pragma unroll 8
  for (int kk = 0; kk < K_IN / 32; ++kk)
    acc = MFMA16(*reinterpret_cast<const short8*>(a_in_base + kk * 32),
                 *reinterpret_cast<const short8*>(&s_win[n * K_IN + ((k0 + kk * 32) ^ swz_n)]),
                 acc);

  for (int t = 0; t < T_; ++t) {
    // ---- wait for h[t] (all WGs' step t-1 stores are at MALL) ----
    if (t > 0) {
      if (wave == 0) {
        const unsigned tgt = (unsigned)t * 8u;
        for (;;) {
          unsigned v = 0xFFFFFFFFu;
          if (lane < 32)
            v = __hip_atomic_load(bars + lane * 32, __ATOMIC_RELAXED, __HIP_MEMORY_SCOPE_AGENT);
          if (__all((int)(lane >= 32 || v >= tgt))) break;
          __builtin_amdgcn_s_sleep(2);
        }
        // order wave0's subsequent h loads after the poll: workgroup-scope
        // acquire = s_waitcnt only, NO cache maintenance
        __builtin_amdgcn_fence(__ATOMIC_ACQUIRE, "workgroup");
        if (lane == 0)
          __hip_atomic_store(&rel_flag, t, __ATOMIC_RELEASE, __HIP_MEMORY_SCOPE_WORKGROUP);
      } else {
        while (__hip_atomic_load(&rel_flag, __ATOMIC_ACQUIRE, __HIP_MEMORY_SCOPE_WORKGROUP) < t)
          __builtin_amdgcn_s_sleep(1);
      }
    }

    // ---- recurrent GEMM: h[slab t] @ W_hh^T (plain cached loads) ----
    const unsigned short* a_h = hrec + (size_t)(T_ - t) * BH + (size_t)arow * H_ + k0;
    #pragma unroll 8
    for (int kk = 0; kk < H_ / 32; ++kk) {
      short8 av = *reinterpret_cast<const short8*>(a_h + kk * 32);
      short8 bv = *reinterpret_cast<const short8*>(&s_whh[n * H_ + ((k0 + kk * 32) ^ swz_n)]);
      acc = MFMA16(av, bv, acc);
    }
    acc[0] += bias_n; acc[1] += bias_n; acc[2] += bias_n; acc[3] += bias_n;

    // ---- redistribute gates within the wave, elementwise ----
    const int rsel  = (lane >> 2) & 3;
    const int sbase = (lane & 48) | (lane & 3);
    float pg[4];
    #pragma unroll
    for (int g = 0; g < 4; ++g) {
      int src = sbase | (g << 2);
      float t0 = __shfl(acc[0], src, 64);
      float t1 = __shfl(acc[1], src, 64);
      float t2 = __shfl(acc[2], src, 64);
      float t3 = __shfl(acc[3], src, 64);
      pg[g] = (rsel == 0) ? t0 : (rsel == 1) ? t1 : (rsel == 2) ? t2 : t3;
    }
    float gi = sigm(pg[0]);
    float gf = sigm(pg[1]);
    float gg = tanhx(pg[2]);
    float go = sigm(pg[3]);
    cst = gf * cst + gi * gg;
    float hv = go * tanhx(cst);

    // pack 4 units for batch eb into one u64, write-through store to slab t+1
    unsigned hv16 = f2bf(hv) & 0xFFFFu;
    const int lb = lane & ~3;
    unsigned v1 = __shfl(hv16, lb | 1, 64);
    unsigned v2 = __shfl(hv16, lb | 2, 64);
    unsigned v3 = __shfl(hv16, lb | 3, 64);
    if (eu == 0) {
      unsigned long long qv = (unsigned long long)(hv16 | (v1 << 16)) |
                              ((unsigned long long)(v2 | (v3 << 16)) << 32);
      unsigned long long* dst = (unsigned long long*)
          (hrec + (size_t)(T_ - t - 1) * BH + (size_t)eb * H_ + j0);
      __hip_atomic_store(dst, qv, __ATOMIC_RELAXED, __HIP_MEMORY_SCOPE_AGENT);
    }

    // ---- arrive: __syncthreads drains vmcnt(0) => h stores ack'd at MALL.
    //      RELAXED RMW (no wbl2!) is then ordered-enough: consumers that
    //      observe the counter observe the h data. ----
    __syncthreads();
    if (tid == 0)
      __hip_atomic_fetch_add(grp, 1u, __ATOMIC_RELAXED, __HIP_MEMORY_SCOPE_AGENT);

    // ---- input GEMM for t+1 (in the arrive->release shadow) ----
    const int tn = (t + 1 < T_) ? t + 1 : t;
    f32x4 na = {0.f, 0.f, 0.f, 0.f};
    const unsigned short* a_in = a_in_base + (long long)tn * in_stride_t;
    #pragma unroll 8
    for (int kk = 0; kk < K_IN / 32; ++kk)
      na = MFMA16(*reinterpret_cast<const short8*>(a_in + kk * 32),
                  *reinterpret_cast<const short8*>(&s_win[n * K_IN + ((k0 + kk * 32) ^ swz_n)]),
                  na);
    acc = na;
  }
}

__global__ void out_head(const unsigned short* __restrict__ h2,
                         const float* __restrict__ W_out,
                         const float* __restrict__ b_out,
                         float* __restrict__ out) {
  int b = blockIdx.x;      // 64
  int lane = threadIdx.x;  // 64 (one wave)
  float s = 0.f;
  for (int k = lane; k < H_; k += 64)
    s += bf2f(h2[(size_t)b * H_ + k]) * W_out[k];
  #pragma unroll
  for (int off = 32; off; off >>= 1) s += __shfl_down(s, off, 64);
  if (lane == 0) out[b] = sigm(s + b_out[0]);
}

} // namespace

extern "C" void kernel_launch(void* const* d_in, const int* in_sizes, int n_in,
                              void* d_out, int out_size, void* d_ws, size_t ws_size,
                              hipStream_t stream) {
  const float* x    = (const float*)d_in[0];
  const float* Wih0 = (const float*)d_in[1];
  const float* Whh0 = (const float*)d_in[2];
  const float* bih0 = (const float*)d_in[3];
  const float* bhh0 = (const float*)d_in[4];
  const float* Wih1 = (const float*)d_in[5];
  const float* Whh1 = (const float*)d_in[6];
  const float* bih1 = (const float*)d_in[7];
  const float* bhh1 = (const float*)d_in[8];
  const float* Wout = (const float*)d_in[9];
  const float* bout = (const float*)d_in[10];
  float* out = (float*)d_out;

  char* ws = (char*)d_ws;
  size_t off = 0;
  auto alloc = [&](size_t bytes) -> char* {
    char* p = ws + off;
    off += (bytes + 4095) & ~(size_t)4095;   // 4KB-align every region
    return p;
  };
  const size_t REC = (size_t)(T_ + 1) * BH * 2;       // 67.2 MB (513 slabs)

  unsigned* bar        = (unsigned*)alloc(16384);     // 4096 u32: L0 at 0, L1 at 2048
  unsigned short* xb   = (unsigned short*)alloc((size_t)B_ * T_ * I_ * 2);
  unsigned short* wih0 = (unsigned short*)alloc((size_t)4 * H_ * I_ * 2);
  unsigned short* whh0 = (unsigned short*)alloc((size_t)4 * H_ * H_ * 2);
  unsigned short* wih1 = (unsigned short*)alloc((size_t)4 * H_ * H_ * 2);
  unsigned short* whh1 = (unsigned short*)alloc((size_t)4 * H_ * H_ * 2);
  unsigned short* h1   = (unsigned short*)alloc(REC);
  unsigned short* h2   = (unsigned short*)alloc(REC);

  auto cvt = [&](const float* s, unsigned short* d, int nelem) {
    int n4 = nelem / 4;
    cvt_bf16_k<<<(n4 + 255) / 256, 256, 0, stream>>>(s, d, n4);
  };
  cvt(x,    xb,   B_ * T_ * I_);
  cvt(Wih0, wih0, 4 * H_ * I_);
  cvt(Whh0, whh0, 4 * H_ * H_);
  cvt(Wih1, wih1, 4 * H_ * H_);
  cvt(Whh1, whh1, 4 * H_ * H_);
  zero_init_k<<<(BH + 255) / 256, 256, 0, stream>>>(h1, h2, bar);

  // layer 0: xb [B][T][I] bf16 (stride_t=I, stride_b=T*I), fresh reversed record
  lstm_layer<I_><<<NWG, NTHR, 0, stream>>>(
      xb, (long long)I_, (long long)T_ * I_,
      wih0, whh0, bih0, bhh0, h1, bar);

  // layer 1: input h1 slabs s=1..512 at h1+(T_-s)*BH -> base h1+(T_-1)*BH,
  // stride_t = -BH; within-slab [b][k]: stride_b = H
  lstm_layer<H_><<<NWG, NTHR, 0, stream>>>(
      h1 + (size_t)(T_ - 1) * BH, -(long long)BH, (long long)H_,
      wih1, whh1, bih1, bhh1, h2, bar + 2048);

  // final h2 = slab T at reversed offset 0
  out_head<<<B_, 64, 0, stream>>>(h2, Wout, bout, out);
}